// Round 9
// baseline (246.939 us; speedup 1.0000x reference)
//
#include <hip/hip_runtime.h>
#include <hip/hip_bf16.h>
#include <stdint.h>

// ---- types -----------------------------------------------------------------
typedef __bf16 bf16_t;
typedef __bf16 bf16x8 __attribute__((ext_vector_type(8)));
typedef __bf16 bf16x4 __attribute__((ext_vector_type(4)));
typedef float  f32x4  __attribute__((ext_vector_type(4)));

#define MFMA16(a, b, c) __builtin_amdgcn_mfma_f32_16x16x32_bf16((a), (b), (c), 0, 0, 0)

__device__ __forceinline__ void gload_lds16(const void* g, void* l) {
  __builtin_amdgcn_global_load_lds((const __attribute__((address_space(1))) void*)g,
                                   (__attribute__((address_space(3))) void*)l, 16, 0, 0);
}

// ---- problem constants -----------------------------------------------------
// B=2, N=4096, NY=4096, ENC=768, DEC=512, H=8, D=64, SCALE=0.125
#define QSCALE 0.18033688011112042f
#define NE_X   4194304UL
#define NE_Y   6291456UL
#define NE_WQ  262144UL
#define NE_WKV 786432UL
#define NE_WP  262144UL
#define NE_BP  512UL

// ---- FAST prep: pure convert (dtype resolved on host) ----------------------
// blocks 0..5760 convert; blocks 5761..5792 decode mask (mfmt host-known).
// mfmt: 0=bool8, 2=bf16, 4=4-byte (u32 bit-test, exact for i32 and f32 0/1).
template <int ISBF>
__global__ void prep_fast(const void* __restrict__ x, const void* __restrict__ y,
                          const void* __restrict__ wq, const void* __restrict__ wkv,
                          const void* __restrict__ wp, const void* __restrict__ bp,
                          const uint8_t* __restrict__ mk,
                          uint16_t* __restrict__ dst, bf16_t* __restrict__ mmul,
                          int mfmt) {
  const int t = threadIdx.x;
  const int bid = blockIdx.x;

  if (bid >= 5761) {
    const int i = (bid - 5761) * 256 + t;  // [0,8192)
    bool on;
    if (mfmt == 0)      on = mk[i] != 0;
    else if (mfmt == 2) on = (((const uint16_t*)mk)[i] & 0x7FFF) != 0;
    else                on = (((const uint32_t*)mk)[i] & 0x7FFFFFFFu) != 0;
    mmul[i] = on ? (bf16_t)0.0f : (bf16_t)1.0f;  // mask=true means EXCLUDE
    return;
  }

  const size_t E0 = NE_X, E1 = E0 + NE_Y, E2 = E1 + NE_WQ, E3 = E2 + NE_WKV,
               E4 = E3 + NE_WP, E5 = E4 + NE_BP;
  size_t i8 = ((size_t)bid * 256 + t) * 8;
  if (i8 >= E5) return;
  const void* src; size_t off;
  if      (i8 < E0) { src = x;   off = i8; }
  else if (i8 < E1) { src = y;   off = i8 - E0; }
  else if (i8 < E2) { src = wq;  off = i8 - E1; }
  else if (i8 < E3) { src = wkv; off = i8 - E2; }
  else if (i8 < E4) { src = wp;  off = i8 - E3; }
  else              { src = bp;  off = i8 - E4; }
  const bool isWq = (i8 >= E1 && i8 < E2);
  if (ISBF && !isWq) {
    *(uint4*)(dst + i8) = *(const uint4*)((const uint16_t*)src + off);
    return;
  }
  float v[8];
  if (ISBF) {  // bf16 source (Wq path): unpack
    const uint16_t* u = (const uint16_t*)src + off;
    for (int j = 0; j < 8; ++j) {
      union { uint32_t q; float f; } c; c.q = ((uint32_t)u[j]) << 16; v[j] = c.f;
    }
  } else {
    const float* f = (const float*)src + off;
    float4 a = *(const float4*)f;
    float4 b2 = *(const float4*)(f + 4);
    v[0] = a.x; v[1] = a.y; v[2] = a.z; v[3] = a.w;
    v[4] = b2.x; v[5] = b2.y; v[6] = b2.z; v[7] = b2.w;
  }
  const float sc = isWq ? QSCALE : 1.0f;
  union { bf16_t h[8]; uint4 u; } pk;
  for (int j = 0; j < 8; ++j) pk.h[j] = (bf16_t)(v[j] * sc);
  *(uint4*)(dst + i8) = pk.u;
}

// ---- SLOW prep (fallback if in_sizes semantics unexpected): self-detect ----
__global__ void prep_slow(const void* __restrict__ x, const void* __restrict__ y,
                          const void* __restrict__ wq, const void* __restrict__ wkv,
                          const void* __restrict__ wp, const void* __restrict__ bp,
                          const uint8_t* __restrict__ mk,
                          uint16_t* __restrict__ dst, int* __restrict__ flags,
                          bf16_t* __restrict__ mmul) {
  const int t = threadIdx.x;
  const int bid = blockIdx.x;
  __shared__ int cbf;
  if (t == 0) cbf = 0;
  __syncthreads();
  {
    const uint16_t* xu = (const uint16_t*)x;
    int local = 0;
    for (int j = 0; j < 8; ++j) {
      int i = t * 8 + j;
      uint16_t u = xu[2 * i];
      int e = (u >> 7) & 0xFF;
      if (u == 0 || (e >= 0x66 && e <= 0x88)) local++;
    }
    atomicAdd(&cbf, local);
  }
  __syncthreads();
  const bool isbf = (cbf > 1536);

  if (bid >= 5761) {
    const int mb = bid - 5761;
    __shared__ int c3f1, c3f3, cnz;
    if (t == 0) { c3f1 = 0; c3f3 = 0; cnz = 0; }
    __syncthreads();
    int l1 = 0, l3 = 0, lnz = 0;
    for (int i = t; i < 4096; i += 256) {
      uint8_t bb = mk[i];
      int p = i & 3;
      if (p == 1 && bb == 0x3F) l1++;
      if (p == 3 && bb == 0x3F) l3++;
      if (p != 0 && bb != 0) lnz++;
    }
    atomicAdd(&c3f1, l1);
    atomicAdd(&c3f3, l3);
    atomicAdd(&cnz, lnz);
    __syncthreads();
    if (mb == 0 && t == 0) flags[0] = isbf ? 1 : 0;
    const int fmt = (c3f1 > 0) ? 2 : (c3f3 > 0) ? 3 : (cnz > 0) ? 0 : 1;
    const int i = mb * 256 + t;
    bool on;
    if (fmt == 0)      on = mk[i] != 0;
    else if (fmt == 1) on = ((const int*)mk)[i] != 0;
    else if (fmt == 2) on = (((const uint16_t*)mk)[i] & 0x7FFF) != 0;
    else               on = ((const float*)mk)[i] != 0.0f;
    mmul[i] = on ? (bf16_t)0.0f : (bf16_t)1.0f;
    return;
  }

  const size_t E0 = NE_X, E1 = E0 + NE_Y, E2 = E1 + NE_WQ, E3 = E2 + NE_WKV,
               E4 = E3 + NE_WP, E5 = E4 + NE_BP;
  size_t i8 = ((size_t)bid * 256 + t) * 8;
  if (i8 >= E5) return;
  const void* src; size_t off;
  if      (i8 < E0) { src = x;   off = i8; }
  else if (i8 < E1) { src = y;   off = i8 - E0; }
  else if (i8 < E2) { src = wq;  off = i8 - E1; }
  else if (i8 < E3) { src = wkv; off = i8 - E2; }
  else if (i8 < E4) { src = wp;  off = i8 - E3; }
  else              { src = bp;  off = i8 - E4; }
  const bool isWq = (i8 >= E1 && i8 < E2);
  if (isbf && !isWq) {
    *(uint4*)(dst + i8) = *(const uint4*)((const uint16_t*)src + off);
    return;
  }
  float v[8];
  if (isbf) {
    const uint16_t* u = (const uint16_t*)src + off;
    for (int j = 0; j < 8; ++j) {
      union { uint32_t q; float f; } c; c.q = ((uint32_t)u[j]) << 16; v[j] = c.f;
    }
  } else {
    const float* f = (const float*)src + off;
    float4 a = *(const float4*)f;
    float4 b2 = *(const float4*)(f + 4);
    v[0] = a.x; v[1] = a.y; v[2] = a.z; v[3] = a.w;
    v[4] = b2.x; v[5] = b2.y; v[6] = b2.z; v[7] = b2.w;
  }
  const float sc = isWq ? QSCALE : 1.0f;
  union { bf16_t h[8]; uint4 u; } pk;
  for (int j = 0; j < 8; ++j) pk.h[j] = (bf16_t)(v[j] * sc);
  *(uint4*)(dst + i8) = pk.u;
}

// ---- GEMM core: C[M x Nc] = A[M x K] @ W[Nc x K]^T, 128x128 tile, BK=32 ----
// 2-phase double-buffered K-loop (R7-proven): stage ks+1, vmcnt(4), raw bars.
template <int K, int MODE>
__device__ __forceinline__ void gemm_core(const bf16_t* __restrict__ A,
                                          const bf16_t* __restrict__ W,
                                          const bf16_t* __restrict__ bias,
                                          void* __restrict__ C,
                                          bf16_t* __restrict__ Vt,
                                          int obf,
                                          int Ncols, int bx, int by, char* lds) {
  const int t = threadIdx.x;
  const int w = t >> 6, lane = t & 63, quad = lane >> 4, l16 = lane & 15;
  const int wr = w >> 1, wc = w & 1;
  const int m0 = by * 128, n0 = bx * 128;

  f32x4 acc[4][4] = {};
  const int rowS = t >> 2, uS = t & 3;
  constexpr int NK = K / 32;

  auto stage = [&](int ks, int buf) {
    char* ldsA = lds + buf * 16384;
    char* ldsW = ldsA + 8192;
    const int k0 = ks * 32;
    for (int i = 0; i < 2; ++i) {
      int row = i * 64 + rowS;
      int c = uS ^ ((row >> 1) & 3);
      gload_lds16(A + (size_t)(m0 + row) * K + k0 + c * 8, ldsA + i * 4096 + w * 1024);
      gload_lds16(W + (size_t)(n0 + row) * K + k0 + c * 8, ldsW + i * 4096 + w * 1024);
    }
  };

  stage(0, 0);
  for (int ks = 0; ks < NK; ++ks) {
    const int cur = ks & 1;
    if (ks + 1 < NK) {
      stage(ks + 1, cur ^ 1);                           // issue next-tile loads
      asm volatile("s_waitcnt vmcnt(4)" ::: "memory");  // drain cur's 4 loads only
    } else {
      asm volatile("s_waitcnt vmcnt(0)" ::: "memory");
    }
    __builtin_amdgcn_sched_barrier(0);
    __builtin_amdgcn_s_barrier();                       // cur buffer visible
    const char* ldsA = lds + cur * 16384;
    const char* ldsW = ldsA + 8192;
    bf16x8 af[4], bfr[4];
    for (int mt = 0; mt < 4; ++mt) {
      int row = wr * 64 + mt * 16 + l16;
      int us = quad ^ ((row >> 1) & 3);
      af[mt] = *(const bf16x8*)(ldsA + row * 64 + us * 16);
    }
    for (int nt = 0; nt < 4; ++nt) {
      int row = wc * 64 + nt * 16 + l16;
      int us = quad ^ ((row >> 1) & 3);
      bfr[nt] = *(const bf16x8*)(ldsW + row * 64 + us * 16);
    }
    for (int mt = 0; mt < 4; ++mt)
      for (int nt = 0; nt < 4; ++nt)
        acc[mt][nt] = MFMA16(af[mt], bfr[nt], acc[mt][nt]);
    __builtin_amdgcn_s_barrier();                       // reads done before reuse
  }

  const int mbase = m0 + wr * 64;
  for (int nt = 0; nt < 4; ++nt) {
    const int col = n0 + wc * 64 + nt * 16 + l16;
    if (MODE == 1 && col >= 512) {
      const int hd = col - 512;                  // h*64 + d
      const int hh = hd >> 6, d = hd & 63;
      const int dt = d >> 4, l15 = d & 15;
      for (int mt = 0; mt < 4; ++mt) {
        int m = mbase + mt * 16 + quad * 4;      // +r over r
        int bb = m >> 12, keyg = m & 4095;
        int kt = keyg >> 6, keyin = keyg & 63;
        int kc = (keyin >> 5) & 1, jq = (keyin >> 3) & 3, j0 = keyin & 7;  // j0 in {0,4}
        const bf16_t* mmp = bias + bb * 4096 + keyg;
        union { bf16_t h4[4]; uint2 u; } pk;
        for (int r = 0; r < 4; ++r) pk.h4[r] = (bf16_t)(acc[mt][nt][r] * (float)mmp[r]);
        size_t base = (((size_t)(bb * 8 + hh) * 64 + kt) * 8 + dt * 2 + kc) * 1024
                      + (jq * 16 + l15) * 16 + j0 * 2;
        *(uint2*)((char*)Vt + base) = pk.u;
      }
    } else if (MODE == 1) {
      for (int mt = 0; mt < 4; ++mt) {
        int m = mbase + mt * 16 + quad * 4;
        for (int r = 0; r < 4; ++r)
          ((bf16_t*)C)[(size_t)(m + r) * 512 + col] = (bf16_t)acc[mt][nt][r];
      }
    } else if (MODE == 0) {
      for (int mt = 0; mt < 4; ++mt) {
        int m = mbase + mt * 16 + quad * 4;
        for (int r = 0; r < 4; ++r)
          ((bf16_t*)C)[(size_t)(m + r) * Ncols + col] = (bf16_t)acc[mt][nt][r];
      }
    } else {  // MODE 2
      const float bv = (float)bias[col];
      const bool ob = (obf != 0);
      for (int mt = 0; mt < 4; ++mt) {
        int m = mbase + mt * 16 + quad * 4;
        for (int r = 0; r < 4; ++r) {
          float v = acc[mt][nt][r] + bv;
          if (ob) ((bf16_t*)C)[(size_t)(m + r) * Ncols + col] = (bf16_t)v;
          else    ((float*)C)[(size_t)(m + r) * Ncols + col] = v;
        }
      }
    }
  }
}

// ---- fused KV + Q projection: blocks [0,512) = KV, [512,768) = Q -----------
__launch_bounds__(256, 2)
__global__ void gemm_kvq(const bf16_t* __restrict__ Yb, const bf16_t* __restrict__ Wkvb,
                         const bf16_t* __restrict__ mmul, bf16_t* __restrict__ Kbuf,
                         bf16_t* __restrict__ Vfrag,
                         const bf16_t* __restrict__ Xb, const bf16_t* __restrict__ Wqb,
                         bf16_t* __restrict__ Qbuf) {
  __shared__ __align__(16) char lds[32768];
  const int bid = blockIdx.x;
  if (bid < 512) {
    gemm_core<768, 1>(Yb, Wkvb, mmul, (void*)Kbuf, Vfrag, 0, 1024,
                      bid & 7, bid >> 3, lds);
  } else {
    const int q = bid - 512;
    gemm_core<512, 0>(Xb, Wqb, nullptr, (void*)Qbuf, nullptr, 0, 512,
                      q & 3, q >> 2, lds);
  }
}

// ---- output projection (MODE 2), obf host-resolved (or flags fallback) -----
__launch_bounds__(256, 2)
__global__ void gemm_out(const bf16_t* __restrict__ A, const bf16_t* __restrict__ W,
                         const bf16_t* __restrict__ bias, void* __restrict__ C,
                         int obf_host, const int* __restrict__ flags) {
  __shared__ __align__(16) char lds[32768];
  const int obf = (obf_host >= 0) ? obf_host : flags[0];
  gemm_core<512, 2>(A, W, bias, C, nullptr, obf, 512,
                    blockIdx.x, blockIdx.y, lds);
}

// ---- fused flash attention, 256 q / block, 32 q / wave, 8 waves ------------
// (unchanged from R6-R8 best)
__launch_bounds__(512, 2)
__global__ void attn(const bf16_t* __restrict__ Qb, const bf16_t* __restrict__ Kb,
                     const bf16_t* __restrict__ Vfb, const bf16_t* __restrict__ mmul,
                     bf16_t* __restrict__ Ob) {
  const int t = threadIdx.x, w = t >> 6, lane = t & 63, quad = lane >> 4, l16 = lane & 15;
  const int bid = blockIdx.x;
  const int h = bid & 7;            // XCD-pinned
  const int b = (bid >> 3) & 1;
  const int q0 = (bid >> 4) * 256;  // 16 q-blocks of 256

  __shared__ __align__(16) char lds[114688];
  // K ring: 10 slots x 8KB = [0, 81920); tile kt -> slot kt%10.
  // P: [81920, 114688) = 8 waves x 4KB (2KB per ng).
  // Q staging overlays ring slots 6..9 ([49152, 81920), 32KB).
  char* Pw = lds + 81920 + w * 4096;
  char* Qs = lds + 49152;

  const bf16_t* Kbase = Kb + (size_t)(b * 4096) * 512 + h * 64;
  const char* Vfbase = (const char*)Vfb + (size_t)(b * 8 + h) * 524288;  // 64*8*1024

  const int srow = t >> 3;            // 0..63 staging row
  const int sc8 = t & 7;

  auto stage_tile = [&](int kt, int slot) {
    int c = sc8 ^ (srow & 7);
    gload_lds16(Kbase + (size_t)(kt * 64 + srow) * 512 + c * 8,
                lds + slot * 8192 + w * 1024);
  };

  // ---- prologue: stage K tiles 0..5 (slots 0..5) + Q (overlay slots 6..9) --
  for (int kt = 0; kt < 6; ++kt) stage_tile(kt, kt);
  for (int i = 0; i < 4; ++i) {
    int row = i * 64 + srow;
    int c = sc8 ^ (row & 7);
    gload_lds16(Qb + (size_t)(b * 4096 + q0 + row) * 512 + h * 64 + c * 8,
                Qs + i * 8192 + w * 1024);
  }
  asm volatile("s_waitcnt vmcnt(0)" ::: "memory");
  __builtin_amdgcn_sched_barrier(0);
  __builtin_amdgcn_s_barrier();

  bf16x8 qf[2][2];
  for (int ng = 0; ng < 2; ++ng)
    for (int kc = 0; kc < 2; ++kc) {
      int row = 32 * w + 16 * ng + l16;
      int u = (4 * kc + quad) ^ (l16 & 7);
      qf[ng][kc] = *(const bf16x8*)(Qs + row * 128 + u * 16);
    }
  asm volatile("s_waitcnt lgkmcnt(0)" ::: "memory");
  __builtin_amdgcn_sched_barrier(0);
  __builtin_amdgcn_s_barrier();
  // stage tiles 6,7 into slots 6,7 (Q region now dead)
  stage_tile(6, 6);
  stage_tile(7, 7);

  f32x4 o[2][4] = {};
  f32x4 lacc[2] = {};
  const int u0 = quad ^ (l16 & 7), u1 = (4 + quad) ^ (l16 & 7);

  auto process = [&](int kt, int slot) {
    const int kt0 = kt * 64;
    // mask + V fragments from global (L1-hot), issued first
    bf16x8 mf0 = *(const bf16x8*)(mmul + b * 4096 + kt0 + quad * 8);
    bf16x8 mf1 = *(const bf16x8*)(mmul + b * 4096 + kt0 + 32 + quad * 8);
    const char* Vtile = Vfbase + (size_t)kt * 8192;
    bf16x8 vf[4][2];
    for (int dt = 0; dt < 4; ++dt)
      for (int kc = 0; kc < 2; ++kc)
        vf[dt][kc] = *(const bf16x8*)(Vtile + (dt * 2 + kc) * 1024 + lane * 16);
    // K fragments (LDS)
    const char* Kl = lds + slot * 8192;
    bf16x8 kf[4][2];
    for (int mt = 0; mt < 4; ++mt) {
      kf[mt][0] = *(const bf16x8*)(Kl + (mt * 16 + l16) * 128 + u0 * 16);
      kf[mt][1] = *(const bf16x8*)(Kl + (mt * 16 + l16) * 128 + u1 * 16);
    }
    // QK for both q-groups (MFMA cluster)
    f32x4 z[2][4];
    __builtin_amdgcn_s_setprio(1);
    for (int ng = 0; ng < 2; ++ng)
      for (int mt = 0; mt < 4; ++mt) {
        f32x4 zz = {};
        zz = MFMA16(kf[mt][0], qf[ng][0], zz);
        z[ng][mt] = MFMA16(kf[mt][1], qf[ng][1], zz);
      }
    __builtin_amdgcn_s_setprio(0);
    // softmax -> P (per-wave LDS, 2KB per ng) -> pf -> l + PV
    for (int ng = 0; ng < 2; ++ng) {
      char* Pn = Pw + ng * 2048;
      for (int mt = 0; mt < 4; ++mt) {
        bf16x4 pk;
        pk.x = (bf16_t)__builtin_amdgcn_exp2f(z[ng][mt][0]);
        pk.y = (bf16_t)__builtin_amdgcn_exp2f(z[ng][mt][1]);
        pk.z = (bf16_t)__builtin_amdgcn_exp2f(z[ng][mt][2]);
        pk.w = (bf16_t)__builtin_amdgcn_exp2f(z[ng][mt][3]);
        int c2 = (2 * mt + (quad >> 1)) ^ (l16 & 7);
        *(bf16x4*)(Pn + l16 * 128 + c2 * 16 + (quad & 1) * 8) = pk;
      }
      bf16x8 pf0 = *(const bf16x8*)(Pn + l16 * 128 + u0 * 16);
      bf16x8 pf1 = *(const bf16x8*)(Pn + l16 * 128 + u1 * 16);
      __builtin_amdgcn_s_setprio(1);
      lacc[ng] = MFMA16(pf0, mf0, lacc[ng]);
      lacc[ng] = MFMA16(pf1, mf1, lacc[ng]);
      for (int dt = 0; dt < 4; ++dt) {
        o[ng][dt] = MFMA16(pf0, vf[dt][0], o[ng][dt]);
        o[ng][dt] = MFMA16(pf1, vf[dt][1], o[ng][dt]);
      }
      __builtin_amdgcn_s_setprio(0);
    }
  };

  // ---- main loop: 32 pairs, 2 raw barriers/pair, counted vmcnt -------------
  int sA = 0, sB = 1;  // slots of tiles 2pg, 2pg+1 (kt % 10)
  for (int pg = 0; pg < 32; ++pg) {
    // staged-K completion guard: outstanding staging <= 6 => tiles <= 2pg+1 done
    if (pg < 29) { asm volatile("s_waitcnt vmcnt(6)" ::: "memory"); }
    else         { asm volatile("s_waitcnt vmcnt(0)" ::: "memory"); }
    __builtin_amdgcn_sched_barrier(0);
    __builtin_amdgcn_s_barrier();
    const int ktA = pg * 2;
    process(ktA, sA);
    process(ktA + 1, sB);
    // stage tiles ktA+8, ktA+9 (slots (sA+8)%10, (sB+8)%10): ring distance
    // guarantees no conflict with slots being read this pair. Issued BEFORE
    // the end barrier so vf-use waits above stay counted (not vmcnt(0)).
    if (ktA + 8 < 64) {
      int s8A = sA + 8; if (s8A >= 10) s8A -= 10;
      int s8B = sB + 8; if (s8B >= 10) s8B -= 10;
      stage_tile(ktA + 8, s8A);
      stage_tile(ktA + 9, s8B);
    }
    __builtin_amdgcn_s_barrier();  // readers done before those slots rewritten
    sA += 2; if (sA >= 10) sA -= 10;
    sB += 2; if (sB >= 10) sB -= 10;
  }

  // epilogue: O / l, store bf16 (C-layout, no shuffles)
  for (int ng = 0; ng < 2; ++ng) {
    float inv[4];
    for (int r = 0; r < 4; ++r) inv[r] = 1.0f / lacc[ng][r];
    for (int dt = 0; dt < 4; ++dt)
      for (int r = 0; r < 4; ++r) {
        int q = q0 + 32 * w + 16 * ng + quad * 4 + r;
        int col = h * 64 + dt * 16 + l16;
        Ob[(size_t)(b * 4096 + q) * 512 + col] = (bf16_t)(o[ng][dt][r] * inv[r]);
      }
  }
}

// ---- launch ----------------------------------------------------------------
extern "C" void kernel_launch(void* const* d_in, const int* in_sizes, int n_in,
                              void* d_out, int out_size, void* d_ws, size_t ws_size,
                              hipStream_t stream) {
  const void* x   = d_in[0];
  const void* y   = d_in[1];
  const void* msk = d_in[2];
  const void* Wq  = d_in[3];
  const void* Wkv = d_in[4];
  const void* Wp  = d_in[5];
  const void* bp  = d_in[6];

  char* ws = (char*)d_ws;
  bf16_t* Xb   = (bf16_t*)(ws + 0);           //  8 MB  [8192 x 512]
  bf16_t* Yb   = (bf16_t*)(ws + 8388608);     // 12 MB  [8192 x 768]
  bf16_t* Wqb  = (bf16_t*)(ws + 20971520);    // 0.5 MB (pre-scaled by QSCALE)
  bf16_t* Wkvb = (bf16_t*)(ws + 21495808);    // 1.5 MB
  bf16_t* Wpb  = (bf16_t*)(ws + 23068672);    // 0.5 MB
  bf16_t* bpb  = (bf16_t*)(ws + 23592960);    // 1 KB
  bf16_t* mmul = (bf16_t*)(ws + 23593984);    // 16 KB  [2][4096] 0/1
  int*    flags = (int*)(ws + 23610368);      // 64 B
  bf16_t* Kbuf  = (bf16_t*)(ws + 25165824);   //  8 MB  [8192 x 512]
  bf16_t* Vfrag = (bf16_t*)(ws + 33554432);   //  8 MB  fragment-order V, mask-zeroed
  bf16_t* Qbuf  = (bf16_t*)(ws + 8388608);    //  8 MB  (aliases Yb, dead by then)
  bf16_t* Obuf  = (bf16_t*)(ws + 0);          //  8 MB  (aliases Xb, dead by then)

  // ---- host-side dtype resolution from in_sizes (bytes), with fallback -----
  int isbf = -1;
  if (in_sizes) {
    if (in_sizes[0] == (int)(NE_X * 4)) isbf = 0;        // f32 x
    else if (in_sizes[0] == (int)(NE_X * 2)) isbf = 1;   // bf16 x
  }
  int mfmt = -1;
  if (in_sizes) {
    if (in_sizes[2] == 8192)       mfmt = 0;             // bool8
    else if (in_sizes[2] == 16384) mfmt = 2;             // bf16
    else if (in_sizes[2] == 32768) mfmt = 4;             // i32/f32 (bit test)
  }
  const bool fast = (isbf >= 0 && mfmt >= 0);

  if (fast) {
    if (isbf)
      hipLaunchKernelGGL((prep_fast<1>), dim3(5793), dim3(256), 0, stream,
                         x, y, Wq, Wkv, Wp, bp, (const uint8_t*)msk,
                         (uint16_t*)ws, mmul, mfmt);
    else
      hipLaunchKernelGGL((prep_fast<0>), dim3(5793), dim3(256), 0, stream,
                         x, y, Wq, Wkv, Wp, bp, (const uint8_t*)msk,
                         (uint16_t*)ws, mmul, mfmt);
  } else {
    hipLaunchKernelGGL(prep_slow, dim3(5793), dim3(256), 0, stream,
                       x, y, Wq, Wkv, Wp, bp, (const uint8_t*)msk,
                       (uint16_t*)ws, flags, mmul);
  }
  // fused KV projection (V in fragment order, mask-zeroed) + Q projection
  hipLaunchKernelGGL(gemm_kvq, dim3(768), dim3(256), 0, stream,
                     Yb, Wkvb, mmul, Kbuf, Vfrag, Xb, Wqb, Qbuf);
  // fused attention (512 threads = 8 waves x 32q, grid 256, XCD-pinned heads)
  hipLaunchKernelGGL(attn, dim3(256), dim3(512), 0, stream,
                     Qbuf, Kbuf, Vfrag, mmul, Obuf);
  // output projection + bias, dtype host-resolved (flags fallback)
  hipLaunchKernelGGL(gemm_out, dim3(4, 64), dim3(256), 0, stream,
                     Obuf, Wpb, bpb, d_out, isbf, flags);
}

// Round 11
// 226.507 us; speedup vs baseline: 1.0902x; 1.0902x over previous
//
#include <hip/hip_runtime.h>
#include <hip/hip_bf16.h>
#include <stdint.h>

// ---- types -----------------------------------------------------------------
typedef __bf16 bf16_t;
typedef __bf16 bf16x8 __attribute__((ext_vector_type(8)));
typedef __bf16 bf16x4 __attribute__((ext_vector_type(4)));
typedef float  f32x4  __attribute__((ext_vector_type(4)));

#define MFMA16(a, b, c) __builtin_amdgcn_mfma_f32_16x16x32_bf16((a), (b), (c), 0, 0, 0)

__device__ __forceinline__ void gload_lds16(const void* g, void* l) {
  __builtin_amdgcn_global_load_lds((const __attribute__((address_space(1))) void*)g,
                                   (__attribute__((address_space(3))) void*)l, 16, 0, 0);
}

// ---- problem constants -----------------------------------------------------
// B=2, N=4096, NY=4096, ENC=768, DEC=512, H=8, D=64, SCALE=0.125
#define QSCALE 0.18033688011112042f
#define NE_X   4194304UL
#define NE_Y   6291456UL
#define NE_WQ  262144UL
#define NE_WKV 786432UL
#define NE_WP  262144UL
#define NE_BP  512UL

// ---- detect dtype + decode mask to multiplicative bf16 (1=keep, 0=masked) --
__global__ void detect_and_mask(const uint16_t* __restrict__ xu,
                                const uint8_t* __restrict__ mk,
                                int* __restrict__ flags, bf16_t* __restrict__ mmul) {
  __shared__ int cbf, c3f1, c3f3, cnz;
  const int t = threadIdx.x;
  if (t == 0) { cbf = 0; c3f1 = 0; c3f3 = 0; cnz = 0; }
  __syncthreads();
  if (blockIdx.x == 0) {
    int local = 0;
    for (int i = t; i < 2048; i += 256) {
      uint16_t u = xu[2 * i];
      int e = (u >> 7) & 0xFF;
      if (u == 0 || (e >= 0x66 && e <= 0x88)) local++;
    }
    atomicAdd(&cbf, local);
  }
  int l1 = 0, l3 = 0, lnz = 0;
  for (int i = t; i < 4096; i += 256) {
    uint8_t b = mk[i];
    int p = i & 3;
    if (p == 1 && b == 0x3F) l1++;
    if (p == 3 && b == 0x3F) l3++;
    if (p != 0 && b != 0) lnz++;
  }
  atomicAdd(&c3f1, l1);
  atomicAdd(&c3f3, l3);
  atomicAdd(&cnz, lnz);
  __syncthreads();
  if (blockIdx.x == 0 && t == 0) flags[0] = (cbf > 1536) ? 1 : 0;
  const int fmt = (c3f1 > 0) ? 2 : (c3f3 > 0) ? 3 : (cnz > 0) ? 0 : 1;  // 0=bool8 1=i32 2=bf16 3=f32
  const int i = blockIdx.x * 256 + t;  // 32 blocks x 256 = 8192
  bool on;
  if (fmt == 0)      on = mk[i] != 0;
  else if (fmt == 1) on = ((const int*)mk)[i] != 0;
  else if (fmt == 2) on = (((const uint16_t*)mk)[i] & 0x7FFF) != 0;
  else               on = ((const float*)mk)[i] != 0.0f;
  mmul[i] = on ? (bf16_t)0.0f : (bf16_t)1.0f;  // mask=true means EXCLUDE
}

// ---- convert all float inputs to packed bf16 workspace (Wq pre-scaled) -----
__global__ void convert_all(const void* __restrict__ x, const void* __restrict__ y,
                            const void* __restrict__ wq, const void* __restrict__ wkv,
                            const void* __restrict__ wp, const void* __restrict__ bp,
                            uint16_t* __restrict__ dst, const int* __restrict__ flags) {
  const size_t E0 = NE_X, E1 = E0 + NE_Y, E2 = E1 + NE_WQ, E3 = E2 + NE_WKV,
               E4 = E3 + NE_WP, E5 = E4 + NE_BP;
  size_t i8 = ((size_t)blockIdx.x * 256 + threadIdx.x) * 8;
  if (i8 >= E5) return;
  const void* src; size_t off;
  if      (i8 < E0) { src = x;   off = i8; }
  else if (i8 < E1) { src = y;   off = i8 - E0; }
  else if (i8 < E2) { src = wq;  off = i8 - E1; }
  else if (i8 < E3) { src = wkv; off = i8 - E2; }
  else if (i8 < E4) { src = wp;  off = i8 - E3; }
  else              { src = bp;  off = i8 - E4; }
  const bool isWq = (i8 >= E1 && i8 < E2);
  if (flags[0] && !isWq) {
    *(uint4*)(dst + i8) = *(const uint4*)((const uint16_t*)src + off);
    return;
  }
  float v[8];
  if (flags[0]) {  // bf16 source (Wq path): unpack
    const uint16_t* u = (const uint16_t*)src + off;
    for (int j = 0; j < 8; ++j) {
      union { uint32_t q; float f; } c; c.q = ((uint32_t)u[j]) << 16; v[j] = c.f;
    }
  } else {
    const float* f = (const float*)src + off;
    float4 a = *(const float4*)f;
    float4 b2 = *(const float4*)(f + 4);
    v[0] = a.x; v[1] = a.y; v[2] = a.z; v[3] = a.w;
    v[4] = b2.x; v[5] = b2.y; v[6] = b2.z; v[7] = b2.w;
  }
  const float sc = isWq ? QSCALE : 1.0f;
  union { bf16_t h[8]; uint4 u; } pk;
  for (int j = 0; j < 8; ++j) pk.h[j] = (bf16_t)(v[j] * sc);
  *(uint4*)(dst + i8) = pk.u;
}

// ---- GEMM: C[M x Nc] = A[M x K] @ W[Nc x K]^T, 128x128 tile, BK=64 ---------
// 2-phase double-buffered K-loop, BK=64 (two proven 32-k sub-tiles per buffer):
// halves barrier count vs BK=32 at the same 2-blocks/CU occupancy (64KB LDS).
// stage ks+1 (8 gload_lds/thread) -> vmcnt(8) drains only ks's loads.
template <int K, int MODE>
__launch_bounds__(256, 2)
__global__ void gemm_bt(const bf16_t* __restrict__ A, const bf16_t* __restrict__ W,
                        const bf16_t* __restrict__ bias, void* __restrict__ C,
                        bf16_t* __restrict__ Vt, const int* __restrict__ flags, int Ncols) {
  __shared__ __align__(16) char lds[65536];   // 2 bufs x (A 16KB + W 16KB)
  const int t = threadIdx.x;
  const int w = t >> 6, lane = t & 63, quad = lane >> 4, l16 = lane & 15;
  const int wr = w >> 1, wc = w & 1;
  const int m0 = blockIdx.y * 128, n0 = blockIdx.x * 128;

  f32x4 acc[4][4] = {};
  const int rowS = t >> 2, uS = t & 3;
  constexpr int NK = K / 64;

  auto stage = [&](int ks, int buf) {
    char* ldsA = lds + buf * 32768;
    char* ldsW = ldsA + 16384;
    const int k0 = ks * 64;
    for (int s = 0; s < 2; ++s)
      for (int i = 0; i < 2; ++i) {
        int row = i * 64 + rowS;
        int c = uS ^ ((row >> 1) & 3);
        gload_lds16(A + (size_t)(m0 + row) * K + k0 + s * 32 + c * 8,
                    ldsA + s * 8192 + i * 4096 + w * 1024);
        gload_lds16(W + (size_t)(n0 + row) * K + k0 + s * 32 + c * 8,
                    ldsW + s * 8192 + i * 4096 + w * 1024);
      }
  };

  stage(0, 0);
  for (int ks = 0; ks < NK; ++ks) {
    const int cur = ks & 1;
    if (ks + 1 < NK) {
      stage(ks + 1, cur ^ 1);                           // issue next-tile loads
      asm volatile("s_waitcnt vmcnt(8)" ::: "memory");  // drain cur's 8 loads only
    } else {
      asm volatile("s_waitcnt vmcnt(0)" ::: "memory");
    }
    __builtin_amdgcn_sched_barrier(0);
    __builtin_amdgcn_s_barrier();                       // cur buffer visible
    for (int s = 0; s < 2; ++s) {
      const char* ldsA = lds + cur * 32768 + s * 8192;
      const char* ldsW = lds + cur * 32768 + 16384 + s * 8192;
      bf16x8 af[4], bfr[4];
      for (int mt = 0; mt < 4; ++mt) {
        int row = wr * 64 + mt * 16 + l16;
        int us = quad ^ ((row >> 1) & 3);
        af[mt] = *(const bf16x8*)(ldsA + row * 64 + us * 16);
      }
      for (int nt = 0; nt < 4; ++nt) {
        int row = wc * 64 + nt * 16 + l16;
        int us = quad ^ ((row >> 1) & 3);
        bfr[nt] = *(const bf16x8*)(ldsW + row * 64 + us * 16);
      }
      for (int mt = 0; mt < 4; ++mt)
        for (int nt = 0; nt < 4; ++nt)
          acc[mt][nt] = MFMA16(af[mt], bfr[nt], acc[mt][nt]);
    }
    __builtin_amdgcn_s_barrier();                       // reads done before reuse
  }

  const int mbase = m0 + wr * 64;
  for (int nt = 0; nt < 4; ++nt) {
    const int col = n0 + wc * 64 + nt * 16 + l16;
    if (MODE == 1 && col >= 512) {
      const int hd = col - 512;                  // h*64 + d
      const int hh = hd >> 6, d = hd & 63;
      const int dt = d >> 4, l15 = d & 15;
      for (int mt = 0; mt < 4; ++mt) {
        int m = mbase + mt * 16 + quad * 4;      // +r over r
        int bb = m >> 12, keyg = m & 4095;
        int kt = keyg >> 6, keyin = keyg & 63;
        int kc = (keyin >> 5) & 1, jq = (keyin >> 3) & 3, j0 = keyin & 7;  // j0 in {0,4}
        const bf16_t* mmp = bias + bb * 4096 + keyg;
        union { bf16_t h4[4]; uint2 u; } pk;
        for (int r = 0; r < 4; ++r) pk.h4[r] = (bf16_t)(acc[mt][nt][r] * (float)mmp[r]);
        size_t base = (((size_t)(bb * 8 + hh) * 64 + kt) * 8 + dt * 2 + kc) * 1024
                      + (jq * 16 + l15) * 16 + j0 * 2;
        *(uint2*)((char*)Vt + base) = pk.u;
      }
    } else if (MODE == 1) {
      for (int mt = 0; mt < 4; ++mt) {
        int m = mbase + mt * 16 + quad * 4;
        for (int r = 0; r < 4; ++r)
          ((bf16_t*)C)[(size_t)(m + r) * 512 + col] = (bf16_t)acc[mt][nt][r];
      }
    } else if (MODE == 0) {
      for (int mt = 0; mt < 4; ++mt) {
        int m = mbase + mt * 16 + quad * 4;
        for (int r = 0; r < 4; ++r)
          ((bf16_t*)C)[(size_t)(m + r) * Ncols + col] = (bf16_t)acc[mt][nt][r];
      }
    } else {  // MODE 2
      const float bv = (float)bias[col];
      const bool obf = (flags[0] != 0);
      for (int mt = 0; mt < 4; ++mt) {
        int m = mbase + mt * 16 + quad * 4;
        for (int r = 0; r < 4; ++r) {
          float v = acc[mt][nt][r] + bv;
          if (obf) ((bf16_t*)C)[(size_t)(m + r) * Ncols + col] = (bf16_t)v;
          else     ((float*)C)[(size_t)(m + r) * Ncols + col] = v;
        }
      }
    }
  }
}

// ---- fused flash attention, 256 q / block, 32 q / wave, 8 waves ------------
// (unchanged from R6-R9 best)
__launch_bounds__(512, 2)
__global__ void attn(const bf16_t* __restrict__ Qb, const bf16_t* __restrict__ Kb,
                     const bf16_t* __restrict__ Vfb, const bf16_t* __restrict__ mmul,
                     bf16_t* __restrict__ Ob) {
  const int t = threadIdx.x, w = t >> 6, lane = t & 63, quad = lane >> 4, l16 = lane & 15;
  const int bid = blockIdx.x;
  const int h = bid & 7;            // XCD-pinned
  const int b = (bid >> 3) & 1;
  const int q0 = (bid >> 4) * 256;  // 16 q-blocks of 256

  __shared__ __align__(16) char lds[114688];
  // K ring: 10 slots x 8KB = [0, 81920); tile kt -> slot kt%10.
  // P: [81920, 114688) = 8 waves x 4KB (2KB per ng).
  // Q staging overlays ring slots 6..9 ([49152, 81920), 32KB).
  char* Pw = lds + 81920 + w * 4096;
  char* Qs = lds + 49152;

  const bf16_t* Kbase = Kb + (size_t)(b * 4096) * 512 + h * 64;
  const char* Vfbase = (const char*)Vfb + (size_t)(b * 8 + h) * 524288;  // 64*8*1024

  const int srow = t >> 3;            // 0..63 staging row
  const int sc8 = t & 7;

  auto stage_tile = [&](int kt, int slot) {
    int c = sc8 ^ (srow & 7);
    gload_lds16(Kbase + (size_t)(kt * 64 + srow) * 512 + c * 8,
                lds + slot * 8192 + w * 1024);
  };

  // ---- prologue: stage K tiles 0..5 (slots 0..5) + Q (overlay slots 6..9) --
  for (int kt = 0; kt < 6; ++kt) stage_tile(kt, kt);
  for (int i = 0; i < 4; ++i) {
    int row = i * 64 + srow;
    int c = sc8 ^ (row & 7);
    gload_lds16(Qb + (size_t)(b * 4096 + q0 + row) * 512 + h * 64 + c * 8,
                Qs + i * 8192 + w * 1024);
  }
  asm volatile("s_waitcnt vmcnt(0)" ::: "memory");
  __builtin_amdgcn_sched_barrier(0);
  __builtin_amdgcn_s_barrier();

  bf16x8 qf[2][2];
  for (int ng = 0; ng < 2; ++ng)
    for (int kc = 0; kc < 2; ++kc) {
      int row = 32 * w + 16 * ng + l16;
      int u = (4 * kc + quad) ^ (l16 & 7);
      qf[ng][kc] = *(const bf16x8*)(Qs + row * 128 + u * 16);
    }
  asm volatile("s_waitcnt lgkmcnt(0)" ::: "memory");
  __builtin_amdgcn_sched_barrier(0);
  __builtin_amdgcn_s_barrier();
  // stage tiles 6,7 into slots 6,7 (Q region now dead)
  stage_tile(6, 6);
  stage_tile(7, 7);

  f32x4 o[2][4] = {};
  f32x4 lacc[2] = {};
  const int u0 = quad ^ (l16 & 7), u1 = (4 + quad) ^ (l16 & 7);

  auto process = [&](int kt, int slot) {
    const int kt0 = kt * 64;
    // mask + V fragments from global (L1-hot), issued first
    bf16x8 mf0 = *(const bf16x8*)(mmul + b * 4096 + kt0 + quad * 8);
    bf16x8 mf1 = *(const bf16x8*)(mmul + b * 4096 + kt0 + 32 + quad * 8);
    const char* Vtile = Vfbase + (size_t)kt * 8192;
    bf16x8 vf[4][2];
    for (int dt = 0; dt < 4; ++dt)
      for (int kc = 0; kc < 2; ++kc)
        vf[dt][kc] = *(const bf16x8*)(Vtile + (dt * 2 + kc) * 1024 + lane * 16);
    // K fragments (LDS)
    const char* Kl = lds + slot * 8192;
    bf16x8 kf[4][2];
    for (int mt = 0; mt < 4; ++mt) {
      kf[mt][0] = *(const bf16x8*)(Kl + (mt * 16 + l16) * 128 + u0 * 16);
      kf[mt][1] = *(const bf16x8*)(Kl + (mt * 16 + l16) * 128 + u1 * 16);
    }
    // QK for both q-groups (MFMA cluster)
    f32x4 z[2][4];
    __builtin_amdgcn_s_setprio(1);
    for (int ng = 0; ng < 2; ++ng)
      for (int mt = 0; mt < 4; ++mt) {
        f32x4 zz = {};
        zz = MFMA16(kf[mt][0], qf[ng][0], zz);
        z[ng][mt] = MFMA16(kf[mt][1], qf[ng][1], zz);
      }
    __builtin_amdgcn_s_setprio(0);
    // softmax -> P (per-wave LDS, 2KB per ng) -> pf -> l + PV
    for (int ng = 0; ng < 2; ++ng) {
      char* Pn = Pw + ng * 2048;
      for (int mt = 0; mt < 4; ++mt) {
        bf16x4 pk;
        pk.x = (bf16_t)__builtin_amdgcn_exp2f(z[ng][mt][0]);
        pk.y = (bf16_t)__builtin_amdgcn_exp2f(z[ng][mt][1]);
        pk.z = (bf16_t)__builtin_amdgcn_exp2f(z[ng][mt][2]);
        pk.w = (bf16_t)__builtin_amdgcn_exp2f(z[ng][mt][3]);
        int c2 = (2 * mt + (quad >> 1)) ^ (l16 & 7);
        *(bf16x4*)(Pn + l16 * 128 + c2 * 16 + (quad & 1) * 8) = pk;
      }
      bf16x8 pf0 = *(const bf16x8*)(Pn + l16 * 128 + u0 * 16);
      bf16x8 pf1 = *(const bf16x8*)(Pn + l16 * 128 + u1 * 16);
      __builtin_amdgcn_s_setprio(1);
      lacc[ng] = MFMA16(pf0, mf0, lacc[ng]);
      lacc[ng] = MFMA16(pf1, mf1, lacc[ng]);
      for (int dt = 0; dt < 4; ++dt) {
        o[ng][dt] = MFMA16(pf0, vf[dt][0], o[ng][dt]);
        o[ng][dt] = MFMA16(pf1, vf[dt][1], o[ng][dt]);
      }
      __builtin_amdgcn_s_setprio(0);
    }
  };

  // ---- main loop: 32 pairs, 2 raw barriers/pair, counted vmcnt -------------
  int sA = 0, sB = 1;  // slots of tiles 2pg, 2pg+1 (kt % 10)
  for (int pg = 0; pg < 32; ++pg) {
    // staged-K completion guard: outstanding staging <= 6 => tiles <= 2pg+1 done
    if (pg < 29) { asm volatile("s_waitcnt vmcnt(6)" ::: "memory"); }
    else         { asm volatile("s_waitcnt vmcnt(0)" ::: "memory"); }
    __builtin_amdgcn_sched_barrier(0);
    __builtin_amdgcn_s_barrier();
    const int ktA = pg * 2;
    process(ktA, sA);
    process(ktA + 1, sB);
    // stage tiles ktA+8, ktA+9 (slots (sA+8)%10, (sB+8)%10): ring distance
    // guarantees no conflict with slots being read this pair. Issued BEFORE
    // the end barrier so vf-use waits above stay counted (not vmcnt(0)).
    if (ktA + 8 < 64) {
      int s8A = sA + 8; if (s8A >= 10) s8A -= 10;
      int s8B = sB + 8; if (s8B >= 10) s8B -= 10;
      stage_tile(ktA + 8, s8A);
      stage_tile(ktA + 9, s8B);
    }
    __builtin_amdgcn_s_barrier();  // readers done before those slots rewritten
    sA += 2; if (sA >= 10) sA -= 10;
    sB += 2; if (sB >= 10) sB -= 10;
  }

  // epilogue: O / l, store bf16 (C-layout, no shuffles)
  for (int ng = 0; ng < 2; ++ng) {
    float inv[4];
    for (int r = 0; r < 4; ++r) inv[r] = 1.0f / lacc[ng][r];
    for (int dt = 0; dt < 4; ++dt)
      for (int r = 0; r < 4; ++r) {
        int q = q0 + 32 * w + 16 * ng + quad * 4 + r;
        int col = h * 64 + dt * 16 + l16;
        Ob[(size_t)(b * 4096 + q) * 512 + col] = (bf16_t)(o[ng][dt][r] * inv[r]);
      }
  }
}

// ---- launch ----------------------------------------------------------------
extern "C" void kernel_launch(void* const* d_in, const int* in_sizes, int n_in,
                              void* d_out, int out_size, void* d_ws, size_t ws_size,
                              hipStream_t stream) {
  const void* x   = d_in[0];
  const void* y   = d_in[1];
  const void* msk = d_in[2];
  const void* Wq  = d_in[3];
  const void* Wkv = d_in[4];
  const void* Wp  = d_in[5];
  const void* bp  = d_in[6];

  char* ws = (char*)d_ws;
  bf16_t* Xb   = (bf16_t*)(ws + 0);           //  8 MB  [8192 x 512]
  bf16_t* Yb   = (bf16_t*)(ws + 8388608);     // 12 MB  [8192 x 768]
  bf16_t* Wqb  = (bf16_t*)(ws + 20971520);    // 0.5 MB (pre-scaled by QSCALE)
  bf16_t* Wkvb = (bf16_t*)(ws + 21495808);    // 1.5 MB
  bf16_t* Wpb  = (bf16_t*)(ws + 23068672);    // 0.5 MB
  bf16_t* bpb  = (bf16_t*)(ws + 23592960);    // 1 KB
  bf16_t* mmul = (bf16_t*)(ws + 23593984);    // 16 KB  [2][4096] 0/1
  int*    flags = (int*)(ws + 23610368);      // 64 B
  bf16_t* Kbuf  = (bf16_t*)(ws + 25165824);   //  8 MB  [8192 x 512]
  bf16_t* Vfrag = (bf16_t*)(ws + 33554432);   //  8 MB  fragment-order V, mask-zeroed
  bf16_t* Qbuf  = (bf16_t*)(ws + 8388608);    //  8 MB  (aliases Yb, dead by then)
  bf16_t* Obuf  = (bf16_t*)(ws + 0);          //  8 MB  (aliases Xb, dead by then)

  hipLaunchKernelGGL(detect_and_mask, dim3(32), dim3(256), 0, stream,
                     (const uint16_t*)x, (const uint8_t*)msk, flags, mmul);
  hipLaunchKernelGGL(convert_all, dim3(5761), dim3(256), 0, stream,
                     x, y, Wq, Wkv, Wp, bp, (uint16_t*)ws, flags);
  // KV projection; V side written in MFMA fragment order + mask-zeroed
  hipLaunchKernelGGL((gemm_bt<768, 1>), dim3(8, 64), dim3(256), 0, stream,
                     Yb, Wkvb, mmul, (void*)Kbuf, Vfrag, flags, 1024);
  // Q projection (scores pre-scaled via Wqb)
  hipLaunchKernelGGL((gemm_bt<512, 0>), dim3(4, 64), dim3(256), 0, stream,
                     Xb, Wqb, (const bf16_t*)nullptr, (void*)Qbuf, (bf16_t*)nullptr, flags, 512);
  // fused attention (512 threads = 8 waves x 32q, grid 256, XCD-pinned heads)
  hipLaunchKernelGGL(attn, dim3(256), dim3(512), 0, stream,
                     Qbuf, Kbuf, Vfrag, mmul, Obuf);
  // output projection + bias, dtype per flag
  hipLaunchKernelGGL((gemm_bt<512, 2>), dim3(4, 64), dim3(256), 0, stream,
                     Obuf, Wpb, bpb, d_out, (bf16_t*)nullptr, flags, 512);
}